// Round 5
// baseline (182.680 us; speedup 1.0000x reference)
//
#include <hip/hip_runtime.h>

#define IMG 1024
#define BH  16   // output rows per band; 64 bands x 16 images = 1024 wgs = 4/CU

// Barrier-free, LDS-free Perona-Malik iteration with 2-deep row prefetch.
// Each lane owns 4 output cols and redundantly computes a 6-wide flux window
// from an 8-wide input window, so no cross-lane exchange is needed. Loads
// issued at step k are consumed at step k+2 (two rows in flight).
__global__ __launch_bounds__(256, 4)
void pm_sweep(const float* __restrict__ in, float* __restrict__ out) {
    const int tid = threadIdx.x;
    const int c0  = tid << 2;                       // 0..1020
    const int y0  = blockIdx.x * BH;
    const size_t base = (size_t)blockIdx.y << 20;   // * IMG*IMG
    const float* I = in + base;
    float*       O = out + base;

    const bool le = (c0 == 0);          // image left edge lane
    const bool re = (c0 == IMG - 4);    // image right edge lane
    const int aC = le ? 0 : c0 - 2;     // 8B-aligned, in-bounds
    const int bC = re ? IMG - 4 : c0 + 2;

    // register pipelines: input rows (8 wide), flux rows (6 wide x 2 comps)
    float r0[8], r1[8], r2[8];
    float f1x[6], f1y[6], f2x[6], f2y[6];
    #pragma unroll
    for (int j = 0; j < 8; ++j) { r0[j] = 0.f; r1[j] = 0.f; r2[j] = 0.f; }
    #pragma unroll
    for (int j = 0; j < 6; ++j) { f1x[j] = 0.f; f1y[j] = 0.f; f2x[j] = 0.f; f2y[j] = 0.f; }

    const float4 Z = make_float4(0.f, 0.f, 0.f, 0.f);
    // two pending row-loads in flight (parity slots, statically named)
    float4 A0 = Z, B0 = Z, A1 = Z, B1 = Z;
    if (y0 >= 2) {                       // row y0-2 (only band 0 misses)
        const size_t r = (size_t)(y0 - 2) << 10;
        A0 = *(const float4*)(I + r + aC);
        B0 = *(const float4*)(I + r + bC);
    }
    if (y0 >= 1) {                       // row y0-1
        const size_t r = (size_t)(y0 - 1) << 10;
        A1 = *(const float4*)(I + r + aC);
        B1 = *(const float4*)(I + r + bC);
    }

    auto do_step = [&](const int k, float4& PA, float4& PB) {
        const int yld = y0 - 2 + k;

        // ---- commit pending row (loaded 2 steps ago) into input ring ----
        #pragma unroll
        for (int j = 0; j < 8; ++j) { r2[j] = r1[j]; r1[j] = r0[j]; }
        r0[0] = le ? 0.f : PA.x;  r0[1] = le ? 0.f : PA.y;
        r0[2] = le ? PA.x : PA.z; r0[3] = le ? PA.y : PA.w;
        r0[4] = re ? PB.z : PB.x; r0[5] = re ? PB.w : PB.y;
        r0[6] = re ? 0.f : PB.z;  r0[7] = re ? 0.f : PB.w;

        // ---- issue load of row yld+2 into the freed parity slot ----
        if (k < BH + 2) {
            const int row = yld + 2;                 // = y0 + k >= 0 always
            if (row < IMG) {
                const size_t r = (size_t)row << 10;
                PA = *(const float4*)(I + r + aC);
                PB = *(const float4*)(I + r + bC);
            } else { PA = Z; PB = Z; }
        }

        // ---- flux row yf = yld-1 on 6-wide window (cols c0-1..c0+4) ----
        float fNx[6], fNy[6];
        const int yf = yld - 1;
        if (yf >= 0 && yf < IMG) {
            float s[8], d[8];
            #pragma unroll
            for (int j = 0; j < 8; ++j) {
                s[j] = fmaf(2.f, r1[j], r2[j] + r0[j]);   // col sums   (x8 scale)
                d[j] = r0[j] - r2[j];                     // row diffs
            }
            #pragma unroll
            for (int i = 0; i < 6; ++i) {
                const float GX  = s[i+2] - s[i];                     // 8*grad_x
                const float GY  = fmaf(2.f, d[i+1], d[i] + d[i+2]);  // 8*grad_y
                const float m2  = fmaf(GY, GY, GX * GX);
                const float mag = fmaf(m2, 0.015625f, 1e-8f);        // gx^2+gy^2+eps
                const float den = fmaf(mag, 400.f, 1.f);             // 1 + mag/kappa^2
                const float c   = __builtin_amdgcn_rcpf(den);
                fNx[i] = c * GX;                                     // 8*flux_x
                fNy[i] = c * GY;                                     // 8*flux_y
            }
            if (le) { fNx[0] = 0.f; fNy[0] = 0.f; }   // flux zero-padded by conv2
            if (re) { fNx[5] = 0.f; fNy[5] = 0.f; }
        } else {
            #pragma unroll
            for (int i = 0; i < 6; ++i) { fNx[i] = 0.f; fNy[i] = 0.f; }
        }

        // ---- divergence + Euler update, row yd = yld-2 ----
        if (k >= 4) {
            float S[6], D[6];
            #pragma unroll
            for (int j = 0; j < 6; ++j) {
                S[j] = fmaf(2.f, f1x[j], f2x[j] + fNx[j]);
                D[j] = fNy[j] - f2y[j];
            }
            float o[4];
            #pragma unroll
            for (int i = 0; i < 4; ++i) {
                const float DX = S[i+2] - S[i];
                const float DY = fmaf(2.f, D[i+1], D[i] + D[i+2]);
                o[i] = fmaf(DX + DY, 0.00390625f, r2[i+2]);   // in + 0.25*div/64
            }
            const int yd = yld - 2;
            *(float4*)(O + ((size_t)yd << 10) + c0) = make_float4(o[0], o[1], o[2], o[3]);
        }

        // ---- shift flux ring (renamed away by full unroll) ----
        #pragma unroll
        for (int j = 0; j < 6; ++j) {
            f2x[j] = f1x[j]; f2y[j] = f1y[j];
            f1x[j] = fNx[j]; f1y[j] = fNy[j];
        }
    };

    #pragma unroll
    for (int kk = 0; kk < (BH + 4) / 2; ++kk) {
        do_step(2 * kk,     A0, B0);   // even steps: parity-0 slot
        do_step(2 * kk + 1, A1, B1);   // odd  steps: parity-1 slot
    }
}

extern "C" void kernel_launch(void* const* d_in, const int* in_sizes, int n_in,
                              void* d_out, int out_size, void* d_ws, size_t ws_size,
                              hipStream_t stream) {
    const float* img = (const float*)d_in[0];
    float* out = (float*)d_out;
    float* ws  = (float*)d_ws;
    const int N = in_sizes[0] / (IMG * IMG);

    dim3 grid(IMG / BH, N);
    dim3 block(256);
    pm_sweep<<<grid, block, 0, stream>>>(img, out);
    pm_sweep<<<grid, block, 0, stream>>>(out, ws);
    pm_sweep<<<grid, block, 0, stream>>>(ws, out);
}